// Round 2
// baseline (385.327 us; speedup 1.0000x reference)
//
#include <hip/hip_runtime.h>
#include <hip/hip_bf16.h>

// 3D shifted-window attention (Swin), D=H=W=32, WS=8, SS=4, NH=12, HD=32, N=512.
//  - kernel 1: precompute relative-position bias into a __device__ global, bf16,
//    pre-scaled by log2(e), laid out exactly in the S^T MFMA fragment order.
//  - kernel 2: one block per (window, head). K (XOR-swizzled, bits 4-5 only) and
//    V^T staged in LDS as bf16. S^T = mfma(K, Q) per 16x16 tile. Softmax without
//    max-subtraction; shift-mask applied as zeroing via ((n^m) & bm)==0 region
//    test. PV uses a shared k-slot permutation so the S^T accumulator feeds the
//    B operand with zero cross-lane traffic.

typedef __attribute__((ext_vector_type(8))) short short8_t;   // 8 x bf16 (4 VGPRs)
typedef __attribute__((ext_vector_type(4))) float f32x4;

__device__ uint2 g_biasF[12 * 32 * 32 * 64];   // 6.29 MB, rewritten every launch

__device__ __forceinline__ unsigned short f2bf(float f) {
  __hip_bfloat16 h = __float2bfloat16(f);   // RNE; compiler fuses pairs to cvt_pk
  return *reinterpret_cast<unsigned short*>(&h);
}
__device__ __forceinline__ unsigned pkbf2(float lo, float hi) {
  return (unsigned)f2bf(lo) | ((unsigned)f2bf(hi) << 16);
}

// ---------------- bias precompute: g_biasF[((nh*32+qt)*32+t)*64 + lane] = uint2
// of 4 bf16 = bias(n = qt*16 + (lane&15), m = t*16 + 4*(lane>>4) + r) * log2e ---
__global__ void bias_prep_kernel(const float* __restrict__ table) {
  int flat = blockIdx.x * 256 + threadIdx.x;      // 12*32*32*64 = 786432 threads
  int l  = flat & 63;
  int t  = (flat >> 6) & 31;
  int qt = (flat >> 11) & 31;
  int nh = flat >> 16;
  int ln = l & 15, g = l >> 4;
  int n = qt * 16 + ln;
  int dn = n >> 6, hn = (n >> 3) & 7, wn = n & 7;
  unsigned short bf[4];
#pragma unroll
  for (int r = 0; r < 4; ++r) {
    int m = t * 16 + g * 4 + r;
    int dm = m >> 6, hm = (m >> 3) & 7, wm = m & 7;
    int idx = (dn - dm + 7) * 225 + (hn - hm + 7) * 15 + (wn - wm + 7);
    float v = table[idx * 12 + nh] * 1.4426950408889634f;
    bf[r] = f2bf(v);
  }
  g_biasF[flat] = make_uint2((unsigned)bf[0] | ((unsigned)bf[1] << 16),
                             (unsigned)bf[2] | ((unsigned)bf[3] << 16));
}

// ---------------- main attention kernel ----------------
__global__ __launch_bounds__(256, 2) void swin_attn_kernel(
    const float* __restrict__ qkv, float* __restrict__ out) {
  // K: 512 rows x 64B, XOR-swizzled (byte ^= (row&3)<<4, stays inside the 64B
  // row) -> injective mapping, conflict-free b128 reads (8 words/bank = min).
  __shared__ __align__(16) unsigned short Klds[512 * 32];   // 32 KB
  // V^T: 32 rows (hd) x 516 cols (tokens, padded) -> conflict-free b64 reads
  __shared__ __align__(16) unsigned short Vt[32 * 516];     // 33 KB

  const int bid = blockIdx.x;
  // XCD-aware swizzle: xcd = bid%8 gets windows [8x,8x+8) with heads grouped in
  // quads -> bias slice L2-resident, window voxels shared across heads.
  const int xcd = bid & 7;
  const int s = bid >> 3;
  const int quad = s >> 5;
  const int rem = s & 31;
  const int nh = quad * 4 + (rem & 3);
  const int w = xcd * 8 + (rem >> 2);
  const int dblk = w >> 4, hblk = (w >> 2) & 3, wblk = w & 3;
  // shifted-window mask: regions differ iff ((n^m) & bm) != 0
  const int bm = ((dblk == 3) ? 256 : 0) | ((hblk == 3) ? 32 : 0) |
                 ((wblk == 3) ? 4 : 0);
  // roll(-4) on read and roll(+4) on write cancel: voxel = (blk*8 + c + 4) & 31
  const int d0 = dblk * 8 + 4, h0 = hblk * 8 + 4, w0 = wblk * 8 + 4;

  const int tid = threadIdx.x;

  // ---- stage K (swizzled, b128 writes): task = (token m, 16B chunk sc) ----
#pragma unroll 1
  for (int rep = 0; rep < 8; ++rep) {
    int task = tid + rep * 256;        // 0..2047
    int m = task >> 2, sc = task & 3;
    int dd = (d0 + (m >> 6)) & 31;
    int hh = (h0 + ((m >> 3) & 7)) & 31;
    int ww = (w0 + (m & 7)) & 31;
    const float* src = qkv + ((dd * 32 + hh) * 32 + ww) * 1152 + nh + 384 + sc * 96;
    unsigned pk[4];
#pragma unroll
    for (int jj = 0; jj < 4; ++jj) {
      pk[jj] = pkbf2(src[(2 * jj) * 12], src[(2 * jj + 1) * 12]);
    }
    char* dst = (char*)Klds + m * 64 + ((sc * 16) ^ ((m & 3) << 4));
    *(uint4*)dst = make_uint4(pk[0], pk[1], pk[2], pk[3]);
  }
  // ---- stage V^T (thread-per-token, conflict-free short writes) ----
#pragma unroll 1
  for (int rep = 0; rep < 2; ++rep) {
    int m = tid + rep * 256;
    int dd = (d0 + (m >> 6)) & 31;
    int hh = (h0 + ((m >> 3) & 7)) & 31;
    int ww = (w0 + (m & 7)) & 31;
    const float* src = qkv + ((dd * 32 + hh) * 32 + ww) * 1152 + nh + 768;
#pragma unroll
    for (int hd = 0; hd < 32; ++hd) {
      Vt[hd * 516 + m] = f2bf(src[hd * 12]);
    }
  }
  __syncthreads();

  const int l = tid & 63;
  const int wv = tid >> 6;
  const int ln = l & 15;
  const int g = l >> 4;
  constexpr float SCL2E = 0.17677669529663687f * 1.4426950408889634f; // HD^-0.5 * log2e

#pragma unroll 1
  for (int it = 0; it < 8; ++it) {
    const int qt = wv * 8 + it;          // this wave's q-tile (16 rows)
    const int n = qt * 16 + ln;
    int dd = (d0 + (n >> 6)) & 31;
    int hh = (h0 + ((n >> 3) & 7)) & 31;
    int ww = (w0 + (n & 7)) & 31;
    const int vox = (dd * 32 + hh) * 32 + ww;
    const float* qsrc = qkv + vox * 1152 + nh + g * 96;   // hd = g*8 + j

    // Q B-fragment: lane holds col n = l&15, k-slot j = hd g*8 + j
    union { unsigned u[4]; short8_t v; } qf;
#pragma unroll
    for (int jj = 0; jj < 4; ++jj) {
      qf.u[jj] = pkbf2(qsrc[(2 * jj) * 12], qsrc[(2 * jj + 1) * 12]);
    }

    const int nAnd = n & bm;
    const uint2* bp = g_biasF + ((nh * 32 + qt) * 32) * 64 + l;
    float sum = 0.f;
    unsigned pb[64];    // P row-block, bf16-packed, in S^T fragment order

#pragma unroll
    for (int t = 0; t < 32; ++t) {
      // K A-fragment: row m = t*16 + (l&15), slot j = hd g*8+j (swizzled b128)
      const short8_t* kp = (const short8_t*)((const char*)Klds +
          ((t * 16 + ln) * 64 + ((g * 16) ^ ((ln & 3) << 4))));
      f32x4 acc =
          __builtin_amdgcn_mfma_f32_16x16x32_bf16(*kp, qf.v, (f32x4)(0.0f), 0, 0, 0);
      uint2 bw = bp[t * 64];
      // m = t*16 + g*4 + r: bit2 = g&1 (same for all 4 regs), bits 5,8 from t<<4
      const int mAnd = ((t << 4) | ((g & 1) << 2)) & bm;
      const bool keep = (nAnd == mAnd);
      float p0 = exp2f(fmaf(acc.x, SCL2E, __uint_as_float(bw.x << 16)));
      float p1 = exp2f(fmaf(acc.y, SCL2E, __uint_as_float(bw.x & 0xffff0000u)));
      float p2 = exp2f(fmaf(acc.z, SCL2E, __uint_as_float(bw.y << 16)));
      float p3 = exp2f(fmaf(acc.w, SCL2E, __uint_as_float(bw.y & 0xffff0000u)));
      p0 = keep ? p0 : 0.f;
      p1 = keep ? p1 : 0.f;
      p2 = keep ? p2 : 0.f;
      p3 = keep ? p3 : 0.f;
      sum += (p0 + p1) + (p2 + p3);
      pb[2 * t]     = pkbf2(p0, p1);
      pb[2 * t + 1] = pkbf2(p2, p3);
    }

    // row-sum across the 4 lane-groups holding this q-row
    sum += __shfl_xor(sum, 16, 64);
    sum += __shfl_xor(sum, 32, 64);
    const float rinv = 1.0f / sum;

    // PV: O^T[hd][n] += V^T * P^T with shared k-slot permutation
    //   slot j -> m-offset = (j<4 ? 4g+j : 16 + 4g + (j-4)); same on A and B.
    f32x4 o0 = (f32x4)(0.0f), o1 = (f32x4)(0.0f);
#pragma unroll
    for (int c = 0; c < 16; ++c) {
      union { unsigned u[4]; short8_t v; } pf;
      pf.u[0] = pb[4 * c + 0];
      pf.u[1] = pb[4 * c + 1];
      pf.u[2] = pb[4 * c + 2];
      pf.u[3] = pb[4 * c + 3];
      const int col = c * 32 + g * 4;
      union { unsigned u[4]; short8_t v; } a0, a1;
      const unsigned* v00 = (const unsigned*)&Vt[ln * 516 + col];
      const unsigned* v01 = (const unsigned*)&Vt[ln * 516 + col + 16];
      a0.u[0] = v00[0]; a0.u[1] = v00[1]; a0.u[2] = v01[0]; a0.u[3] = v01[1];
      const unsigned* v10 = (const unsigned*)&Vt[(16 + ln) * 516 + col];
      const unsigned* v11 = (const unsigned*)&Vt[(16 + ln) * 516 + col + 16];
      a1.u[0] = v10[0]; a1.u[1] = v10[1]; a1.u[2] = v11[0]; a1.u[3] = v11[1];
      o0 = __builtin_amdgcn_mfma_f32_16x16x32_bf16(a0.v, pf.v, o0, 0, 0, 0);
      o1 = __builtin_amdgcn_mfma_f32_16x16x32_bf16(a1.v, pf.v, o1, 0, 0, 0);
    }

    // O^T D-frag: col n = l&15 (this lane's own q-token), row hd = g*4 + r (+16)
    float* op = out + vox * 384 + nh;
#pragma unroll
    for (int r = 0; r < 4; ++r) {
      op[(g * 4 + r) * 12] = o0[r] * rinv;
      op[(g * 4 + r + 16) * 12] = o1[r] * rinv;
    }
  }
}

extern "C" void kernel_launch(void* const* d_in, const int* in_sizes, int n_in,
                              void* d_out, int out_size, void* d_ws, size_t ws_size,
                              hipStream_t stream) {
  (void)in_sizes; (void)n_in; (void)out_size; (void)d_ws; (void)ws_size;
  const float* qkv = (const float*)d_in[0];          // [1,32,32,32,1152] fp32
  const float* bias_table = (const float*)d_in[1];   // [3375,12] fp32
  float* out = (float*)d_out;                        // [1,32,32,32,384] fp32

  bias_prep_kernel<<<3072, 256, 0, stream>>>(bias_table);
  swin_attn_kernel<<<768, 256, 0, stream>>>(qkv, out);
}

// Round 3
// 352.122 us; speedup vs baseline: 1.0943x; 1.0943x over previous
//
#include <hip/hip_runtime.h>
#include <hip/hip_bf16.h>

// 3D shifted-window attention (Swin), D=H=W=32, WS=8, SS=4, NH=12, HD=32, N=512.
// Pass 0: bias precompute (bf16, pre-scaled by log2e, in S^T fragment order).
// Pass 1: repack qkv fp32 [vox][3,hd,nh] -> bf16 g_pack[part][nh][w][m][hd]
//         (shift baked in), fully coalesced both sides via LDS transpose.
// Pass 2: attention, one block per (window, head); K (XOR-swizzled) + V^T in
//         LDS; S^T = mfma(K,Q); softmax w/o max-subtraction; shift-mask as
//         zeroing via ((n^m)&bm)==0; PV via shared k-slot permutation.

typedef __attribute__((ext_vector_type(8))) short short8_t;   // 8 x bf16
typedef __attribute__((ext_vector_type(4))) float f32x4;

__device__ uint2 g_biasF[12 * 32 * 32 * 64];                  // 6.3 MB
__device__ uint4 g_pack4[3ULL * 12 * 64 * 512 * 32 / 8];      // 75.5 MB bf16

__device__ __forceinline__ unsigned short f2bf(float f) {
  __hip_bfloat16 h = __float2bfloat16(f);   // RNE; pairs fuse to cvt_pk
  return *reinterpret_cast<unsigned short*>(&h);
}
__device__ __forceinline__ unsigned pkbf2(float lo, float hi) {
  return (unsigned)f2bf(lo) | ((unsigned)f2bf(hi) << 16);
}

// ---------------- bias precompute: g_biasF[((nh*32+qt)*32+t)*64 + lane] -------
__global__ void bias_prep_kernel(const float* __restrict__ table) {
  int flat = blockIdx.x * 256 + threadIdx.x;      // 786432 threads
  int l  = flat & 63;
  int t  = (flat >> 6) & 31;
  int qt = (flat >> 11) & 31;
  int nh = flat >> 16;
  int ln = l & 15, g = l >> 4;
  int n = qt * 16 + ln;
  int dn = n >> 6, hn = (n >> 3) & 7, wn = n & 7;
  unsigned short bf[4];
#pragma unroll
  for (int r = 0; r < 4; ++r) {
    int m = t * 16 + g * 4 + r;
    int dm = m >> 6, hm = (m >> 3) & 7, wm = m & 7;
    int idx = (dn - dm + 7) * 225 + (hn - hm + 7) * 15 + (wn - wm + 7);
    float v = table[idx * 12 + nh] * 1.4426950408889634f;
    bf[r] = f2bf(v);
  }
  g_biasF[flat] = make_uint2((unsigned)bf[0] | ((unsigned)bf[1] << 16),
                             (unsigned)bf[2] | ((unsigned)bf[3] << 16));
}

// ---------------- pass 1: repack ----------------
// block = (w, md, mh): 8 voxels (mw=0..7). Coalesced float4 reads -> LDS bf16
// -> 16B packed writes, 512B contiguous per (part,nh).
__global__ __launch_bounds__(256, 4) void repack_kernel(
    const float* __restrict__ qkv) {
  __shared__ unsigned short S[8 * 1154];    // pad 1154 -> bank-friendly
  const int bid = blockIdx.x;               // 64*8*8 = 4096
  const int mh = bid & 7;
  const int md = (bid >> 3) & 7;
  const int w = bid >> 6;
  const int dblk = w >> 4, hblk = (w >> 2) & 3, wblk = w & 3;
  const int dd = (dblk * 8 + 4 + md) & 31;
  const int hh = (hblk * 8 + 4 + mh) & 31;
  const int w0 = wblk * 8 + 4;
  const int tid = threadIdx.x;

  // load 8 voxels x 1152 ch = 2304 float4 tasks
#pragma unroll
  for (int rep = 0; rep < 9; ++rep) {
    int t = rep * 256 + tid;
    unsigned v = (unsigned)t / 288u;
    int c4 = t - (int)v * 288;
    int ww = (w0 + (int)v) & 31;
    const float4 f = *(const float4*)(qkv + (((dd * 32 + hh) * 32 + ww) * 1152) + c4 * 4);
    *(uint2*)&S[v * 1154 + c4 * 4] = make_uint2(pkbf2(f.x, f.y), pkbf2(f.z, f.w));
  }
  __syncthreads();

  const int mbase = md * 64 + mh * 8;
  unsigned short* gp = (unsigned short*)g_pack4;
#pragma unroll
  for (int rep = 0; rep < 5; ++rep) {
    int t = rep * 256 + tid;                 // 1152 tasks
    if (t < 1152) {
      int chunk = t & 3;
      int mw = (t >> 2) & 7;
      int r = t >> 5;                        // 0..35
      int nh = r % 12;
      int part = r / 12;
      int ebase = mw * 1154 + part * 384 + chunk * 96 + nh;
      unsigned pk[4];
#pragma unroll
      for (int jj = 0; jj < 4; ++jj) {
        unsigned lo = S[ebase + (2 * jj) * 12];
        unsigned hi = S[ebase + (2 * jj + 1) * 12];
        pk[jj] = lo | (hi << 16);
      }
      size_t dst = ((((size_t)(part * 12 + nh) * 64 + w) * 512 + mbase + mw) * 32 + chunk * 8);
      *(uint4*)&gp[dst] = make_uint4(pk[0], pk[1], pk[2], pk[3]);
    }
  }
}

// ---------------- pass 2: attention ----------------
__global__ __launch_bounds__(256, 2) void swin_attn_kernel(
    float* __restrict__ out) {
  // K: 512 rows x 64B, XOR-swizzled (byte ^= (row&3)<<4, within-row) ->
  // injective, conflict-free b128 reads/writes.
  __shared__ __align__(16) unsigned short Klds[512 * 32];   // 32 KB
  // V^T: 32 rows (hd) x 516 cols (tokens, padded)
  __shared__ __align__(16) unsigned short Vt[32 * 516];     // 33 KB

  const int bid = blockIdx.x;
  // XCD-aware swizzle: xcd = bid%8 gets 8 windows, heads grouped in quads.
  const int xcd = bid & 7;
  const int s = bid >> 3;
  const int quad = s >> 5;
  const int rem = s & 31;
  const int nh = quad * 4 + (rem & 3);
  const int w = xcd * 8 + (rem >> 2);
  const int dblk = w >> 4, hblk = (w >> 2) & 3, wblk = w & 3;
  const int bm = ((dblk == 3) ? 256 : 0) | ((hblk == 3) ? 32 : 0) |
                 ((wblk == 3) ? 4 : 0);
  const int d0 = dblk * 8 + 4, h0 = hblk * 8 + 4, w0 = wblk * 8 + 4;

  const int tid = threadIdx.x;

  const unsigned short* gp = (const unsigned short*)g_pack4;
  const size_t base = ((size_t)nh * 64 + w) * (512 * 32);
  const unsigned short* Qg = gp + base;                           // part 0
  const unsigned short* Kg = gp + (size_t)1 * 12 * 64 * 512 * 32 + base;
  const unsigned short* Vg = gp + (size_t)2 * 12 * 64 * 512 * 32 + base;

  // ---- stage K: coalesced uint4 loads, swizzled b128 LDS writes ----
#pragma unroll
  for (int it = 0; it < 8; ++it) {
    int flat = it * 256 + tid;               // 0..2047
    int m = flat >> 2, chunk = flat & 3;
    uint4 d = *(const uint4*)(Kg + flat * 8);
    char* dst = (char*)Klds + m * 64 + ((chunk * 16) ^ ((m & 3) << 4));
    *(uint4*)dst = d;
  }
  // ---- stage V: coalesced uint4 loads, transpose to Vt[hd][m] ----
#pragma unroll
  for (int it = 0; it < 8; ++it) {
    int flat = it * 256 + tid;
    int m = flat >> 2, hc = flat & 3;
    uint4 d = *(const uint4*)(Vg + flat * 8);
    const unsigned u[4] = {d.x, d.y, d.z, d.w};
#pragma unroll
    for (int j = 0; j < 8; ++j) {
      unsigned val = (u[j >> 1] >> (16 * (j & 1))) & 0xffffu;
      Vt[(hc * 8 + j) * 516 + m] = (unsigned short)val;
    }
  }
  __syncthreads();

  const int l = tid & 63;
  const int wv = tid >> 6;
  const int ln = l & 15;
  const int g = l >> 4;
  constexpr float SCL2E = 0.17677669529663687f * 1.4426950408889634f; // HD^-0.5 * log2e

#pragma unroll 1
  for (int it = 0; it < 8; ++it) {
    const int qt = wv * 8 + it;          // this wave's q-tile (16 rows)
    const int n = qt * 16 + ln;

    // Q B-fragment: one dwordx4 = hd 8g..8g+7 of token n
    const uint4 qd = *(const uint4*)(Qg + n * 32 + g * 8);
    union { unsigned u[4]; short8_t v; } qf;
    qf.u[0] = qd.x; qf.u[1] = qd.y; qf.u[2] = qd.z; qf.u[3] = qd.w;

    const int nAnd = n & bm;
    const uint2* bp = g_biasF + ((nh * 32 + qt) * 32) * 64 + l;
    float sum = 0.f;
    unsigned pb[64];    // P row-block, bf16-packed, in S^T fragment order

#pragma unroll
    for (int t = 0; t < 32; ++t) {
      // K A-fragment: row m = t*16 + ln, slots hd = 8g..8g+7 (swizzled b128)
      const short8_t* kp = (const short8_t*)((const char*)Klds +
          ((t * 16 + ln) * 64 + ((g * 16) ^ ((ln & 3) << 4))));
      f32x4 acc =
          __builtin_amdgcn_mfma_f32_16x16x32_bf16(*kp, qf.v, (f32x4)(0.0f), 0, 0, 0);
      uint2 bw = bp[t * 64];
      const int mAnd = ((t << 4) | ((g & 1) << 2)) & bm;
      const bool keep = (nAnd == mAnd);
      float p0 = exp2f(fmaf(acc.x, SCL2E, __uint_as_float(bw.x << 16)));
      float p1 = exp2f(fmaf(acc.y, SCL2E, __uint_as_float(bw.x & 0xffff0000u)));
      float p2 = exp2f(fmaf(acc.z, SCL2E, __uint_as_float(bw.y << 16)));
      float p3 = exp2f(fmaf(acc.w, SCL2E, __uint_as_float(bw.y & 0xffff0000u)));
      p0 = keep ? p0 : 0.f;
      p1 = keep ? p1 : 0.f;
      p2 = keep ? p2 : 0.f;
      p3 = keep ? p3 : 0.f;
      sum += (p0 + p1) + (p2 + p3);
      pb[2 * t]     = pkbf2(p0, p1);
      pb[2 * t + 1] = pkbf2(p2, p3);
    }

    // row-sum across the 4 lane-groups holding this q-row
    sum += __shfl_xor(sum, 16, 64);
    sum += __shfl_xor(sum, 32, 64);
    const float rinv = 1.0f / sum;

    // PV: O^T = V^T x P^T with shared k-slot permutation
    f32x4 o0 = (f32x4)(0.0f), o1 = (f32x4)(0.0f);
#pragma unroll
    for (int c = 0; c < 16; ++c) {
      union { unsigned u[4]; short8_t v; } pf;
      pf.u[0] = pb[4 * c + 0];
      pf.u[1] = pb[4 * c + 1];
      pf.u[2] = pb[4 * c + 2];
      pf.u[3] = pb[4 * c + 3];
      const int col = c * 32 + g * 4;
      union { unsigned u[4]; short8_t v; } a0, a1;
      const unsigned* v00 = (const unsigned*)&Vt[ln * 516 + col];
      const unsigned* v01 = (const unsigned*)&Vt[ln * 516 + col + 16];
      a0.u[0] = v00[0]; a0.u[1] = v00[1]; a0.u[2] = v01[0]; a0.u[3] = v01[1];
      const unsigned* v10 = (const unsigned*)&Vt[(16 + ln) * 516 + col];
      const unsigned* v11 = (const unsigned*)&Vt[(16 + ln) * 516 + col + 16];
      a1.u[0] = v10[0]; a1.u[1] = v10[1]; a1.u[2] = v11[0]; a1.u[3] = v11[1];
      o0 = __builtin_amdgcn_mfma_f32_16x16x32_bf16(a0.v, pf.v, o0, 0, 0, 0);
      o1 = __builtin_amdgcn_mfma_f32_16x16x32_bf16(a1.v, pf.v, o1, 0, 0, 0);
    }

    // O^T D-frag: col n = l&15 (lane's own q-token), row hd = g*4 + r (+16)
    int dd = (d0 + (n >> 6)) & 31;
    int hh = (h0 + ((n >> 3) & 7)) & 31;
    int ww = (w0 + (n & 7)) & 31;
    float* op = out + ((dd * 32 + hh) * 32 + ww) * 384 + nh;
#pragma unroll
    for (int r = 0; r < 4; ++r) {
      op[(g * 4 + r) * 12] = o0[r] * rinv;
      op[(g * 4 + r + 16) * 12] = o1[r] * rinv;
    }
  }
}

extern "C" void kernel_launch(void* const* d_in, const int* in_sizes, int n_in,
                              void* d_out, int out_size, void* d_ws, size_t ws_size,
                              hipStream_t stream) {
  (void)in_sizes; (void)n_in; (void)out_size; (void)d_ws; (void)ws_size;
  const float* qkv = (const float*)d_in[0];          // [1,32,32,32,1152] fp32
  const float* bias_table = (const float*)d_in[1];   // [3375,12] fp32
  float* out = (float*)d_out;                        // [1,32,32,32,384] fp32

  bias_prep_kernel<<<3072, 256, 0, stream>>>(bias_table);
  repack_kernel<<<4096, 256, 0, stream>>>(qkv);
  swin_attn_kernel<<<768, 256, 0, stream>>>(out);
}